// Round 6
// baseline (314.913 us; speedup 1.0000x reference)
//
#include <hip/hip_runtime.h>
#include <hip/hip_bf16.h>
#include <math.h>

#define D_MODEL 1024
#define N_HEADS 16
#define D_K     64
#define S_LEN   2048
#define B_SZ    2

typedef unsigned short u16;
typedef unsigned int   u32;
using short8 = __attribute__((ext_vector_type(8))) short;
using f32x4  = __attribute__((ext_vector_type(4))) float;

__device__ inline float bf2f(u16 u) { return __uint_as_float((u32)u << 16); }
__device__ inline u16 f2bf(float f) {
    __hip_bfloat16 h = __float2bfloat16(f);   // RNE
    return *(u16*)&h;
}
__device__ inline u32 pkbf(float lo, float hi) {
    return ((u32)f2bf(hi) << 16) | f2bf(lo);
}
__device__ inline void gload_lds16(const void* g, void* l) {
    __builtin_amdgcn_global_load_lds(
        (const __attribute__((address_space(1))) unsigned int*)g,
        (__attribute__((address_space(3))) unsigned int*)l, 16, 0, 0);
}

// ---------------------------------------------------------------------------
// Fused fp32->bf16 cast of x, W_qkv, W_out (one launch).
// ---------------------------------------------------------------------------
#define N1 (B_SZ * S_LEN * D_MODEL / 4)            // x groups
#define N2 (3 * D_MODEL * D_MODEL / 4)             // W_qkv groups
#define N3 (D_MODEL * D_MODEL / 4)                 // W_out groups

__global__ __launch_bounds__(256)
void cast3_f32_bf16(const float* __restrict__ x, const float* __restrict__ wq,
                    const float* __restrict__ wo, u16* __restrict__ xb,
                    u16* __restrict__ wqb, u16* __restrict__ wob) {
    int i = blockIdx.x * 256 + threadIdx.x;
    const float4* src;
    ushort4* dst;
    if (i < N1)            { src = (const float4*)x  + i;            dst = (ushort4*)xb  + i; }
    else if (i < N1 + N2)  { src = (const float4*)wq + (i - N1);     dst = (ushort4*)wqb + (i - N1); }
    else                   { src = (const float4*)wo + (i - N1 - N2); dst = (ushort4*)wob + (i - N1 - N2); }
    float4 v = *src;
    ushort4 u;
    u.x = f2bf(v.x); u.y = f2bf(v.y); u.z = f2bf(v.z); u.w = f2bf(v.w);
    *dst = u;
}

// ---------------------------------------------------------------------------
// bf16 MFMA GEMM (m97 structure): C[M][N] = A[M][K] * B[N][K]^T.
// EPI=0: fp32 C store. EPI=1 (qkv projection): Q/K col-blocks (col0<2048)
// write bf16 to C (qkv layout); V col-blocks write transposed bf16 into
// VTout[(b*16+h)*64+d][s] as uint2 of 4 consecutive-s values.
// ---------------------------------------------------------------------------
template <int EPI>
__global__ __launch_bounds__(256)
void gemm_bt_mfma(const u16* __restrict__ A, const u16* __restrict__ B,
                  void* __restrict__ Cout, u16* __restrict__ VTout,
                  int M, int N, int K) {
    __shared__ u16 As[128 * 32];
    __shared__ u16 Bs[128 * 32];
    const int tid  = threadIdx.x;
    const int lane = tid & 63;
    const int wv   = tid >> 6;
    const int wm   = wv >> 1, wn = wv & 1;
    const int row0 = blockIdx.y * 128;
    const int col0 = blockIdx.x * 128;

    const int lr = lane >> 2;
    const int lc = (lane & 3) * 8;

    f32x4 acc[4][4] = {};

    for (int k0 = 0; k0 < K; k0 += 32) {
#pragma unroll
        for (int t = 0; t < 2; t++) {
            int rblk = wv * 32 + t * 16;
            gload_lds16(A + (size_t)(row0 + rblk + lr) * K + k0 + lc, &As[rblk * 32]);
            gload_lds16(B + (size_t)(col0 + rblk + lr) * K + k0 + lc, &Bs[rblk * 32]);
        }
        __syncthreads();

        short8 af[4], bfr[4];
#pragma unroll
        for (int mi = 0; mi < 4; mi++)
            af[mi] = *(const short8*)&As[(wm * 64 + mi * 16 + (lane & 15)) * 32 + (lane >> 4) * 8];
#pragma unroll
        for (int nj = 0; nj < 4; nj++)
            bfr[nj] = *(const short8*)&Bs[(wn * 64 + nj * 16 + (lane & 15)) * 32 + (lane >> 4) * 8];
#pragma unroll
        for (int mi = 0; mi < 4; mi++)
#pragma unroll
            for (int nj = 0; nj < 4; nj++)
                acc[mi][nj] = __builtin_amdgcn_mfma_f32_16x16x32_bf16(
                    af[mi], bfr[nj], acc[mi][nj], 0, 0, 0);
        __syncthreads();
    }

    const int cr = (lane >> 4) * 4;
    const int cc = lane & 15;

    if (EPI == 0) {
#pragma unroll
        for (int mi = 0; mi < 4; mi++)
#pragma unroll
            for (int nj = 0; nj < 4; nj++) {
                int c = col0 + wn * 64 + nj * 16 + cc;
#pragma unroll
                for (int r = 0; r < 4; r++) {
                    int rr = row0 + wm * 64 + mi * 16 + cr + r;
                    ((float*)Cout)[(size_t)rr * N + c] = acc[mi][nj][r];
                }
            }
    } else {
        if (col0 >= 2 * D_MODEL) {
            // V block: transposed store to VT (B,H,D,S)
#pragma unroll
            for (int mi = 0; mi < 4; mi++) {
                int rr0 = row0 + wm * 64 + mi * 16 + cr;   // 4 consecutive s
                int bb   = rr0 >> 11;
                int srow = rr0 & (S_LEN - 1);
#pragma unroll
                for (int nj = 0; nj < 4; nj++) {
                    int hd = col0 + wn * 64 + nj * 16 + cc - 2 * D_MODEL;  // h*64+d
                    uint2 pk;
                    pk.x = pkbf(acc[mi][nj][0], acc[mi][nj][1]);
                    pk.y = pkbf(acc[mi][nj][2], acc[mi][nj][3]);
                    *(uint2*)&VTout[((size_t)bb * N_HEADS * D_K + hd) * S_LEN + srow] = pk;
                }
            }
        } else {
            // Q/K block: plain bf16 store into qkv layout
#pragma unroll
            for (int mi = 0; mi < 4; mi++)
#pragma unroll
                for (int nj = 0; nj < 4; nj++) {
                    int c = col0 + wn * 64 + nj * 16 + cc;
#pragma unroll
                    for (int r = 0; r < 4; r++) {
                        int rr = row0 + wm * 64 + mi * 16 + cr + r;
                        ((u16*)Cout)[(size_t)rr * N + c] = f2bf(acc[mi][nj][r]);
                    }
                }
        }
    }
}

// ---------------------------------------------------------------------------
// RoPE in place on bf16 qkv Q and K slices. Q additionally scaled by
// (1/sqrt(d_k)) * log2(e) so attention can use exp2-based softmax.
// ---------------------------------------------------------------------------
__global__ __launch_bounds__(256)
void rope_bf16(u16* __restrict__ qkv, const int* __restrict__ pos) {
    int idx = blockIdx.x * blockDim.x + threadIdx.x;
    int j = idx & 31;
    int h = (idx >> 5) & 15;
    int w = (idx >> 9) & 1;
    int s = (idx >> 10) & 2047;
    int b = idx >> 21;

    float p = (float)pos[s];
    float inv_freq = __powf(10000.0f, -(float)(2 * j) / 64.0f);
    float ang = p * inv_freq;
    float sn, cs;
    sincosf(ang, &sn, &cs);
    float sc = (w == 0) ? 0.125f * 1.44269504f : 1.0f;   // fold log2(e) into Q

    size_t base = (((size_t)(b * S_LEN + s) * 3 + w) * D_MODEL) + h * D_K + 2 * j;
    float x1 = bf2f(qkv[base]);
    float x2 = bf2f(qkv[base + 1]);
    qkv[base]     = f2bf((x1 * cs - x2 * sn) * sc);
    qkv[base + 1] = f2bf((x1 * sn + x2 * cs) * sc);
}

// ---------------------------------------------------------------------------
// MFMA flash attention v3 (causal), S^T formulation + register-pipelined
// staging. Block = 4 waves per (b, h, 64-query tile); wave owns 16 queries.
// Pipeline: K/V tile t+1 is loaded to VGPRs BEFORE computing tile t, and
// written regs->LDS at the top of iteration t+1 — global latency overlaps
// compute instead of stalling at the barrier (fixes R4's exposed vmcnt(0)).
// Softmax in base-2 (Q pre-scaled by log2e/8): exp2f -> raw v_exp_f32.
// ---------------------------------------------------------------------------
__global__ __launch_bounds__(256)
void attn_mfma(const u16* __restrict__ qkv, const u16* __restrict__ VT,
               u16* __restrict__ out) {
    __shared__ u16 Ks[2][64 * 32];    // [kf d-chunk][key*32 + dL]
    __shared__ u16 VsT[2][64 * 32];   // [kc key-chunk][d*32 + kL]
    __shared__ u16 Ps[4][16 * 68];    // per-wave [query 16][key 64 + pad]

    const int tid  = threadIdx.x;
    const int lane = tid & 63;
    const int wv   = tid >> 6;
    const int qt   = gridDim.x - 1 - blockIdx.x;   // longest blocks first
    const int h    = blockIdx.y, b = blockIdx.z;
    const int bh   = b * N_HEADS + h;
    const int q0   = qt * 64;
    const int qw0  = q0 + wv * 16;
    const int l15  = lane & 15;
    const int quad = lane >> 4;
    const int lr   = lane >> 2;
    const int lc   = (lane & 3) * 8;

    const size_t vtb = (size_t)bh * D_K * S_LEN;
    u16* Psw = &Ps[wv][0];

    // Q fragments (B-operand layout); Q pre-scaled by 0.125*log2e in rope.
    short8 qf[2];
#pragma unroll
    for (int kf = 0; kf < 2; kf++)
        qf[kf] = *(const short8*)&qkv[((size_t)(b * S_LEN + qw0 + l15) * 3 + 0) * D_MODEL
                                      + h * D_K + kf * 32 + quad * 8];

    f32x4 acc[4] = {};
    float mq = -INFINITY;
    float lq = 0.f;

    // ---- preload tile 0 into registers ----
    uint4 kreg[2], vreg[2];
#pragma unroll
    for (int kf = 0; kf < 2; kf++)
        kreg[kf] = *(const uint4*)&qkv[((size_t)(b * S_LEN + wv * 16 + lr) * 3 + 1) * D_MODEL
                                       + h * D_K + kf * 32 + lc];
#pragma unroll
    for (int kc = 0; kc < 2; kc++)
        vreg[kc] = *(const uint4*)&VT[vtb + (size_t)(wv * 16 + lr) * S_LEN + kc * 32 + lc];

    for (int kt = 0; kt <= qt; kt++) {
        const int k0 = kt * 64;
        __syncthreads();   // all waves done reading LDS tile t-1
        // regs -> LDS (compiler waits vmcnt for kreg/vreg here; loads were
        // issued one full compute-phase ago)
#pragma unroll
        for (int kf = 0; kf < 2; kf++)
            *(uint4*)&Ks[kf][(wv * 16 + lr) * 32 + lc] = kreg[kf];
#pragma unroll
        for (int kc = 0; kc < 2; kc++)
            *(uint4*)&VsT[kc][(wv * 16 + lr) * 32 + lc] = vreg[kc];
        __syncthreads();   // tile t visible to all waves

        // ---- issue loads for tile t+1 (overlap with compute below) ----
        if (kt < qt) {
            const int k0n = k0 + 64;
#pragma unroll
            for (int kf = 0; kf < 2; kf++)
                kreg[kf] = *(const uint4*)&qkv[((size_t)(b * S_LEN + k0n + wv * 16 + lr) * 3 + 1) * D_MODEL
                                               + h * D_K + kf * 32 + lc];
#pragma unroll
            for (int kc = 0; kc < 2; kc++)
                vreg[kc] = *(const uint4*)&VT[vtb + (size_t)(wv * 16 + lr) * S_LEN + k0n + kc * 32 + lc];
        }

        if (k0 > qw0 + 15) continue;   // wave fully above diagonal

        // ---- S^T = K·Q^T : rows=keys, col=query l15 ----
        f32x4 s[4] = {};
#pragma unroll
        for (int kf = 0; kf < 2; kf++)
#pragma unroll
            for (int nj = 0; nj < 4; nj++) {
                short8 kfr = *(const short8*)&Ks[kf][(nj * 16 + l15) * 32 + quad * 8];
                s[nj] = __builtin_amdgcn_mfma_f32_16x16x32_bf16(kfr, qf[kf], s[nj], 0, 0, 0);
            }

        // ---- causal mask (diagonal tile only) ----
        if (k0 + 63 > qw0) {
            const int row_g = qw0 + l15;
#pragma unroll
            for (int nj = 0; nj < 4; nj++)
#pragma unroll
                for (int r = 0; r < 4; r++) {
                    int key_g = k0 + nj * 16 + quad * 4 + r;
                    if (key_g > row_g) s[nj][r] = -INFINITY;
                }
        }

        // ---- online softmax (base 2): one query per lane ----
        float rmax = s[0][0];
#pragma unroll
        for (int nj = 0; nj < 4; nj++)
#pragma unroll
            for (int r = 0; r < 4; r++) rmax = fmaxf(rmax, s[nj][r]);
        rmax = fmaxf(rmax, __shfl_xor(rmax, 16, 64));
        rmax = fmaxf(rmax, __shfl_xor(rmax, 32, 64));
        float mn = fmaxf(mq, rmax);
        float alpha = exp2f(mq - mn);
        mq = mn;
        float rsum = 0.f;
#pragma unroll
        for (int nj = 0; nj < 4; nj++)
#pragma unroll
            for (int r = 0; r < 4; r++) {
                float p = exp2f(s[nj][r] - mn);
                s[nj][r] = p;
                rsum += p;
            }
        rsum += __shfl_xor(rsum, 16, 64);
        rsum += __shfl_xor(rsum, 32, 64);
        lq = lq * alpha + rsum;

        // ---- rescale O ----
#pragma unroll
        for (int r = 0; r < 4; r++) {
            float ar = __shfl(alpha, quad * 4 + r, 64);
#pragma unroll
            for (int nj = 0; nj < 4; nj++) acc[nj][r] *= ar;
        }

        // ---- P (bf16 pairs) -> wave-private LDS strip [query][key] ----
#pragma unroll
        for (int nj = 0; nj < 4; nj++) {
            uint2 pk;
            pk.x = pkbf(s[nj][0], s[nj][1]);
            pk.y = pkbf(s[nj][2], s[nj][3]);
            *(uint2*)&Psw[l15 * 68 + nj * 16 + quad * 4] = pk;
        }

        // ---- O += P·V ----
#pragma unroll
        for (int kf = 0; kf < 2; kf++) {
            const u16* pp = &Psw[l15 * 68 + kf * 32 + quad * 8];
            uint2 plo = *(const uint2*)pp;
            uint2 phi = *(const uint2*)(pp + 4);
            u32 praw[4] = { plo.x, plo.y, phi.x, phi.y };
            short8 pf = *(const short8*)praw;
#pragma unroll
            for (int nj = 0; nj < 4; nj++) {
                short8 vf = *(const short8*)&VsT[kf][(nj * 16 + l15) * 32 + quad * 8];
                acc[nj] = __builtin_amdgcn_mfma_f32_16x16x32_bf16(pf, vf, acc[nj], 0, 0, 0);
            }
        }
    }

    // ---- epilogue: normalize, store bf16 (B,S,H*D) ----
    float invl = 1.f / lq;
#pragma unroll
    for (int r = 0; r < 4; r++) {
        float ir = __shfl(invl, quad * 4 + r, 64);
        int row_g = qw0 + quad * 4 + r;
#pragma unroll
        for (int nj = 0; nj < 4; nj++)
            out[(size_t)(b * S_LEN + row_g) * D_MODEL + h * D_K + nj * 16 + l15] =
                f2bf(acc[nj][r] * ir);
    }
}

// ---------------------------------------------------------------------------
extern "C" void kernel_launch(void* const* d_in, const int* in_sizes, int n_in,
                              void* d_out, int out_size, void* d_ws, size_t ws_size,
                              hipStream_t stream) {
    const float* x    = (const float*)d_in[0];
    const int*   pos  = (const int*)d_in[1];
    const float* Wqkv = (const float*)d_in[2];
    const float* Wout = (const float*)d_in[3];
    float*       out  = (float*)d_out;

    const int M = B_SZ * S_LEN;   // 4096

    u16* qkvb = (u16*)d_ws;                            // 4096 x 3072 (V slice unused)
    u16* aob  = qkvb + (size_t)M * 3 * D_MODEL;        // 4096 x 1024
    u16* xb   = aob  + (size_t)M * D_MODEL;            // 4096 x 1024
    u16* wqb  = xb   + (size_t)M * D_MODEL;            // 3072 x 1024
    u16* wob  = wqb  + (size_t)3 * D_MODEL * D_MODEL;  // 1024 x 1024
    u16* vtb  = wob  + (size_t)D_MODEL * D_MODEL;      // 4096 x 1024 (B,H,D,S)

    // 0) fused casts (1 launch)
    cast3_f32_bf16<<<(N1 + N2 + N3) / 256, 256, 0, stream>>>(x, Wqkv, Wout, xb, wqb, wob);

    // 1) qkv = x @ W_qkv^T ; V columns written transposed into vtb
    gemm_bt_mfma<1><<<dim3(3 * D_MODEL / 128, M / 128), 256, 0, stream>>>(
        xb, wqb, qkvb, vtb, M, 3 * D_MODEL, D_MODEL);

    // 2) RoPE in place on Q/K (Q scaled by 0.125*log2e)
    rope_bf16<<<(B_SZ * S_LEN * 2 * N_HEADS * 32) / 256, 256, 0, stream>>>(qkvb, pos);

    // 3) MFMA flash attention -> aob (B,S,H*D) bf16
    attn_mfma<<<dim3(S_LEN / 64, N_HEADS, B_SZ), 256, 0, stream>>>(qkvb, vtb, aob);

    // 4) out = ao @ W_out^T (fp32 out)
    gemm_bt_mfma<0><<<dim3(D_MODEL / 128, M / 128), 256, 0, stream>>>(
        aob, wob, out, nullptr, M, D_MODEL, D_MODEL);
}

// Round 7
// 269.171 us; speedup vs baseline: 1.1699x; 1.1699x over previous
//
#include <hip/hip_runtime.h>
#include <hip/hip_bf16.h>
#include <math.h>

#define D_MODEL 1024
#define N_HEADS 16
#define D_K     64
#define S_LEN   2048
#define B_SZ    2

typedef unsigned short u16;
typedef unsigned int   u32;
using short8 = __attribute__((ext_vector_type(8))) short;
using f32x4  = __attribute__((ext_vector_type(4))) float;

__device__ inline float bf2f(u16 u) { return __uint_as_float((u32)u << 16); }
__device__ inline u16 f2bf(float f) {
    __hip_bfloat16 h = __float2bfloat16(f);   // RNE
    return *(u16*)&h;
}
__device__ inline u32 pkbf(float lo, float hi) {
    return ((u32)f2bf(hi) << 16) | f2bf(lo);
}
__device__ inline void gload_lds16(const void* g, void* l) {
    __builtin_amdgcn_global_load_lds(
        (const __attribute__((address_space(1))) unsigned int*)g,
        (__attribute__((address_space(3))) unsigned int*)l, 16, 0, 0);
}

// ---------------------------------------------------------------------------
// Fused fp32->bf16 cast of x, W_qkv, W_out (one launch).
// ---------------------------------------------------------------------------
#define N1 (B_SZ * S_LEN * D_MODEL / 4)
#define N2 (3 * D_MODEL * D_MODEL / 4)
#define N3 (D_MODEL * D_MODEL / 4)

__global__ __launch_bounds__(256)
void cast3_f32_bf16(const float* __restrict__ x, const float* __restrict__ wq,
                    const float* __restrict__ wo, u16* __restrict__ xb,
                    u16* __restrict__ wqb, u16* __restrict__ wob) {
    int i = blockIdx.x * 256 + threadIdx.x;
    const float4* src;
    ushort4* dst;
    if (i < N1)            { src = (const float4*)x  + i;             dst = (ushort4*)xb  + i; }
    else if (i < N1 + N2)  { src = (const float4*)wq + (i - N1);      dst = (ushort4*)wqb + (i - N1); }
    else                   { src = (const float4*)wo + (i - N1 - N2); dst = (ushort4*)wob + (i - N1 - N2); }
    float4 v = *src;
    ushort4 u;
    u.x = f2bf(v.x); u.y = f2bf(v.y); u.z = f2bf(v.z); u.w = f2bf(v.w);
    *dst = u;
}

// ---------------------------------------------------------------------------
// bf16 MFMA GEMM (m97 structure): C[M][N] = A[M][K] * B[N][K]^T. (R2-verified)
// ---------------------------------------------------------------------------
template <bool OUT_BF16>
__global__ __launch_bounds__(256)
void gemm_bt_mfma(const u16* __restrict__ A, const u16* __restrict__ B,
                  void* __restrict__ Cout, int M, int N, int K) {
    __shared__ u16 As[128 * 32];
    __shared__ u16 Bs[128 * 32];
    const int tid  = threadIdx.x;
    const int lane = tid & 63;
    const int wv   = tid >> 6;
    const int wm   = wv >> 1, wn = wv & 1;
    const int row0 = blockIdx.y * 128;
    const int col0 = blockIdx.x * 128;

    const int lr = lane >> 2;
    const int lc = (lane & 3) * 8;

    f32x4 acc[4][4] = {};

    for (int k0 = 0; k0 < K; k0 += 32) {
#pragma unroll
        for (int t = 0; t < 2; t++) {
            int rblk = wv * 32 + t * 16;
            gload_lds16(A + (size_t)(row0 + rblk + lr) * K + k0 + lc, &As[rblk * 32]);
            gload_lds16(B + (size_t)(col0 + rblk + lr) * K + k0 + lc, &Bs[rblk * 32]);
        }
        __syncthreads();

        short8 af[4], bfr[4];
#pragma unroll
        for (int mi = 0; mi < 4; mi++)
            af[mi] = *(const short8*)&As[(wm * 64 + mi * 16 + (lane & 15)) * 32 + (lane >> 4) * 8];
#pragma unroll
        for (int nj = 0; nj < 4; nj++)
            bfr[nj] = *(const short8*)&Bs[(wn * 64 + nj * 16 + (lane & 15)) * 32 + (lane >> 4) * 8];
#pragma unroll
        for (int mi = 0; mi < 4; mi++)
#pragma unroll
            for (int nj = 0; nj < 4; nj++)
                acc[mi][nj] = __builtin_amdgcn_mfma_f32_16x16x32_bf16(
                    af[mi], bfr[nj], acc[mi][nj], 0, 0, 0);
        __syncthreads();
    }

    const int cr = (lane >> 4) * 4;
    const int cc = lane & 15;
#pragma unroll
    for (int mi = 0; mi < 4; mi++) {
#pragma unroll
        for (int nj = 0; nj < 4; nj++) {
            int c = col0 + wn * 64 + nj * 16 + cc;
#pragma unroll
            for (int r = 0; r < 4; r++) {
                int rr = row0 + wm * 64 + mi * 16 + cr + r;
                if (OUT_BF16)
                    ((u16*)Cout)[(size_t)rr * N + c] = f2bf(acc[mi][nj][r]);
                else
                    ((float*)Cout)[(size_t)rr * N + c] = acc[mi][nj][r];
            }
        }
    }
}

// ---------------------------------------------------------------------------
// RoPE in place on bf16 qkv Q/K slices. Q scaled by (1/8)*log2(e) for
// exp2-based softmax downstream.
// ---------------------------------------------------------------------------
__global__ __launch_bounds__(256)
void rope_bf16(u16* __restrict__ qkv, const int* __restrict__ pos) {
    int idx = blockIdx.x * blockDim.x + threadIdx.x;
    int j = idx & 31;
    int h = (idx >> 5) & 15;
    int w = (idx >> 9) & 1;
    int s = (idx >> 10) & 2047;
    int b = idx >> 21;

    float p = (float)pos[s];
    float inv_freq = __powf(10000.0f, -(float)(2 * j) / 64.0f);
    float ang = p * inv_freq;
    float sn, cs;
    sincosf(ang, &sn, &cs);
    float sc = (w == 0) ? 0.125f * 1.44269504f : 1.0f;

    size_t base = (((size_t)(b * S_LEN + s) * 3 + w) * D_MODEL) + h * D_K + 2 * j;
    float x1 = bf2f(qkv[base]);
    float x2 = bf2f(qkv[base + 1]);
    qkv[base]     = f2bf((x1 * cs - x2 * sn) * sc);
    qkv[base + 1] = f2bf((x1 * sn + x2 * cs) * sc);
}

// ---------------------------------------------------------------------------
// V transpose: qkv V slice (B,S,3,H,D) -> VT (B,H,D,S). Coalesced via LDS.
// ---------------------------------------------------------------------------
__global__ __launch_bounds__(256)
void vtrans(const u16* __restrict__ qkv, u16* __restrict__ VT) {
    __shared__ u16 t[64][68];
    const int st = blockIdx.x, h = blockIdx.y, b = blockIdx.z;
    const int tid = threadIdx.x;
    const int bh = b * N_HEADS + h;

#pragma unroll
    for (int i = 0; i < 4; i++) {
        int e  = tid + i * 256;
        int sl = e >> 4;
        int c4 = e & 15;
        ushort4 v = *(const ushort4*)&qkv[((size_t)(b * S_LEN + st * 64 + sl) * 3 + 2) * D_MODEL
                                          + h * D_K + c4 * 4];
        *(ushort4*)&t[sl][c4 * 4] = v;
    }
    __syncthreads();
#pragma unroll
    for (int i = 0; i < 4; i++) {
        int e  = tid + i * 256;
        int d  = e >> 4;
        int s4 = e & 15;
        ushort4 o;
        o.x = t[s4 * 4 + 0][d];
        o.y = t[s4 * 4 + 1][d];
        o.z = t[s4 * 4 + 2][d];
        o.w = t[s4 * 4 + 3][d];
        *(ushort4*)&VT[((size_t)bh * D_K + d) * S_LEN + st * 64 + s4 * 4] = o;
    }
}

// ---------------------------------------------------------------------------
// MFMA flash attention v4 (causal), S^T formulation + DOUBLE-BUFFERED
// global_load_lds staging. Block = 4 waves per (b,h,64-query tile).
// One barrier per k-tile: after barrier(t) [whose compiler vmcnt(0) drain
// guarantees tile t resident], issue DMA for tile t+1 into the other buffer
// (last read at t-1, ordered by barrier t), then compute tile t. The
// prefetch thus has the whole compute phase to land — no exposed latency.
// Softmax base-2 (Q pre-scaled by log2e/8). P via wave-private LDS strip.
// ---------------------------------------------------------------------------
__global__ __launch_bounds__(256)
void attn_mfma(const u16* __restrict__ qkv, const u16* __restrict__ VT,
               u16* __restrict__ out) {
    __shared__ u16 Ks[2][2][64 * 32];    // [buf][kf d-chunk][key*32 + dL]
    __shared__ u16 VsT[2][2][64 * 32];   // [buf][kc key-chunk][d*32 + kL]
    __shared__ u16 Ps[4][16 * 68];       // per-wave [query 16][key 64 + pad]
    // total 41472 B -> 3 blocks/CU

    const int tid  = threadIdx.x;
    const int lane = tid & 63;
    const int wv   = tid >> 6;
    const int qt   = gridDim.x - 1 - blockIdx.x;   // longest blocks first
    const int h    = blockIdx.y, b = blockIdx.z;
    const int bh   = b * N_HEADS + h;
    const int q0   = qt * 64;
    const int qw0  = q0 + wv * 16;
    const int l15  = lane & 15;
    const int quad = lane >> 4;
    const int lr   = lane >> 2;
    const int lc   = (lane & 3) * 8;

    const size_t vtb = (size_t)bh * D_K * S_LEN;
    u16* Psw = &Ps[wv][0];

    // Q fragments (B-operand layout [n=query l15][k=d quad*8+j]); pre-scaled.
    short8 qf[2];
#pragma unroll
    for (int kf = 0; kf < 2; kf++)
        qf[kf] = *(const short8*)&qkv[((size_t)(b * S_LEN + qw0 + l15) * 3 + 0) * D_MODEL
                                      + h * D_K + kf * 32 + quad * 8];

    f32x4 acc[4] = {};
    float mq = -INFINITY;
    float lq = 0.f;

    // ---- prefetch tile 0 into buffer 0 ----
#pragma unroll
    for (int kf = 0; kf < 2; kf++)
        gload_lds16(qkv + ((size_t)(b * S_LEN + wv * 16 + lr) * 3 + 1) * D_MODEL
                        + h * D_K + kf * 32 + lc,
                    &Ks[0][kf][(wv * 16) * 32]);
#pragma unroll
    for (int kc = 0; kc < 2; kc++)
        gload_lds16(VT + vtb + (size_t)(wv * 16 + lr) * S_LEN + kc * 32 + lc,
                    &VsT[0][kc][(wv * 16) * 32]);

    for (int kt = 0; kt <= qt; kt++) {
        const int k0  = kt * 64;
        const int cur = kt & 1;
        __syncthreads();   // vmcnt(0) drain: tile kt resident; prior reads done

        // ---- issue DMA for tile kt+1 into the other buffer ----
        if (kt < qt) {
            const int nxt = cur ^ 1;
            const int k0n = k0 + 64;
#pragma unroll
            for (int kf = 0; kf < 2; kf++)
                gload_lds16(qkv + ((size_t)(b * S_LEN + k0n + wv * 16 + lr) * 3 + 1) * D_MODEL
                                + h * D_K + kf * 32 + lc,
                            &Ks[nxt][kf][(wv * 16) * 32]);
#pragma unroll
            for (int kc = 0; kc < 2; kc++)
                gload_lds16(VT + vtb + (size_t)(wv * 16 + lr) * S_LEN + k0n + kc * 32 + lc,
                            &VsT[nxt][kc][(wv * 16) * 32]);
        }

        if (k0 > qw0 + 15) continue;   // wave fully above diagonal

        // ---- S^T = K·Q^T : rows=keys (quad*4+r), col=query (l15) ----
        f32x4 s[4] = {};
#pragma unroll
        for (int kf = 0; kf < 2; kf++)
#pragma unroll
            for (int nj = 0; nj < 4; nj++) {
                short8 kfr = *(const short8*)&Ks[cur][kf][(nj * 16 + l15) * 32 + quad * 8];
                s[nj] = __builtin_amdgcn_mfma_f32_16x16x32_bf16(kfr, qf[kf], s[nj], 0, 0, 0);
            }

        // ---- causal mask (diagonal tile only) ----
        if (k0 + 63 > qw0) {
            const int row_g = qw0 + l15;
#pragma unroll
            for (int nj = 0; nj < 4; nj++)
#pragma unroll
                for (int r = 0; r < 4; r++) {
                    int key_g = k0 + nj * 16 + quad * 4 + r;
                    if (key_g > row_g) s[nj][r] = -INFINITY;
                }
        }

        // ---- online softmax (base 2): one query per lane ----
        float rmax = s[0][0];
#pragma unroll
        for (int nj = 0; nj < 4; nj++)
#pragma unroll
            for (int r = 0; r < 4; r++) rmax = fmaxf(rmax, s[nj][r]);
        rmax = fmaxf(rmax, __shfl_xor(rmax, 16, 64));
        rmax = fmaxf(rmax, __shfl_xor(rmax, 32, 64));
        float mn = fmaxf(mq, rmax);
        float alpha = exp2f(mq - mn);
        mq = mn;
        float rsum = 0.f;
#pragma unroll
        for (int nj = 0; nj < 4; nj++)
#pragma unroll
            for (int r = 0; r < 4; r++) {
                float p = exp2f(s[nj][r] - mn);
                s[nj][r] = p;
                rsum += p;
            }
        rsum += __shfl_xor(rsum, 16, 64);
        rsum += __shfl_xor(rsum, 32, 64);
        lq = lq * alpha + rsum;

        // ---- rescale O ----
#pragma unroll
        for (int r = 0; r < 4; r++) {
            float ar = __shfl(alpha, quad * 4 + r, 64);
#pragma unroll
            for (int nj = 0; nj < 4; nj++) acc[nj][r] *= ar;
        }

        // ---- P (bf16 pairs) -> wave-private LDS strip [query][key] ----
#pragma unroll
        for (int nj = 0; nj < 4; nj++) {
            uint2 pk;
            pk.x = pkbf(s[nj][0], s[nj][1]);
            pk.y = pkbf(s[nj][2], s[nj][3]);
            *(uint2*)&Psw[l15 * 68 + nj * 16 + quad * 4] = pk;
        }
        // same-wave LDS RAW -> compiler inserts lgkmcnt wait

        // ---- O += P·V : A=P[m=query][k=key], B=VsT[n=d][k=key] ----
#pragma unroll
        for (int kf = 0; kf < 2; kf++) {
            const u16* pp = &Psw[l15 * 68 + kf * 32 + quad * 8];
            uint2 plo = *(const uint2*)pp;
            uint2 phi = *(const uint2*)(pp + 4);
            u32 praw[4] = { plo.x, plo.y, phi.x, phi.y };
            short8 pf = *(const short8*)praw;
#pragma unroll
            for (int nj = 0; nj < 4; nj++) {
                short8 vf = *(const short8*)&VsT[cur][kf][(nj * 16 + l15) * 32 + quad * 8];
                acc[nj] = __builtin_amdgcn_mfma_f32_16x16x32_bf16(pf, vf, acc[nj], 0, 0, 0);
            }
        }
    }

    // ---- epilogue: normalize, store bf16 (B,S,H*D) ----
    float invl = 1.f / lq;
#pragma unroll
    for (int r = 0; r < 4; r++) {
        float ir = __shfl(invl, quad * 4 + r, 64);
        int row_g = qw0 + quad * 4 + r;
#pragma unroll
        for (int nj = 0; nj < 4; nj++)
            out[(size_t)(b * S_LEN + row_g) * D_MODEL + h * D_K + nj * 16 + l15] =
                f2bf(acc[nj][r] * ir);
    }
}

// ---------------------------------------------------------------------------
extern "C" void kernel_launch(void* const* d_in, const int* in_sizes, int n_in,
                              void* d_out, int out_size, void* d_ws, size_t ws_size,
                              hipStream_t stream) {
    const float* x    = (const float*)d_in[0];
    const int*   pos  = (const int*)d_in[1];
    const float* Wqkv = (const float*)d_in[2];
    const float* Wout = (const float*)d_in[3];
    float*       out  = (float*)d_out;

    const int M = B_SZ * S_LEN;   // 4096

    u16* qkvb = (u16*)d_ws;                            // 4096 x 3072
    u16* aob  = qkvb + (size_t)M * 3 * D_MODEL;        // 4096 x 1024
    u16* xb   = aob  + (size_t)M * D_MODEL;            // 4096 x 1024
    u16* wqb  = xb   + (size_t)M * D_MODEL;            // 3072 x 1024
    u16* wob  = wqb  + (size_t)3 * D_MODEL * D_MODEL;  // 1024 x 1024
    u16* vtb  = wob  + (size_t)D_MODEL * D_MODEL;      // 4096 x 1024 (B,H,D,S)

    // 0) fused casts
    cast3_f32_bf16<<<(N1 + N2 + N3) / 256, 256, 0, stream>>>(x, Wqkv, Wout, xb, wqb, wob);

    // 1) qkv = x @ W_qkv^T
    gemm_bt_mfma<true><<<dim3(3 * D_MODEL / 128, M / 128), 256, 0, stream>>>(
        xb, wqb, qkvb, M, 3 * D_MODEL, D_MODEL);

    // 2) RoPE in place (Q scaled by 0.125*log2e)
    rope_bf16<<<(B_SZ * S_LEN * 2 * N_HEADS * 32) / 256, 256, 0, stream>>>(qkvb, pos);

    // 3) V transpose -> (B,H,D,S)
    vtrans<<<dim3(S_LEN / 64, N_HEADS, B_SZ), 256, 0, stream>>>(qkvb, vtb);

    // 4) MFMA flash attention (double-buffered staging) -> aob
    attn_mfma<<<dim3(S_LEN / 64, N_HEADS, B_SZ), 256, 0, stream>>>(qkvb, vtb, aob);

    // 5) out = ao @ W_out^T (fp32 out)
    gemm_bt_mfma<false><<<dim3(D_MODEL / 128, M / 128), 256, 0, stream>>>(
        aob, wob, out, M, D_MODEL, D_MODEL);
}